// Round 3
// baseline (331.864 us; speedup 1.0000x reference)
//
#include <hip/hip_runtime.h>
#include <stdint.h>

#define N_TOKENS 32768
#define N_CODES  8192
#define DIM      256
#define EPSF     1e-8f

typedef __bf16 bf16x8 __attribute__((ext_vector_type(8)));
typedef float  f32x4  __attribute__((ext_vector_type(4)));

// ---------------------------------------------------------------------------
// ws layout: [bf16 codebooks 4MiB][cnorm f32 32KiB][idx i32 128KiB][hist i32 32KiB]
// ---------------------------------------------------------------------------
#define WS_CNORM_OFF  (4u*1024u*1024u)
#define WS_IDX_OFF    (WS_CNORM_OFF + N_CODES*4u)
#define WS_HIST_OFF   (WS_IDX_OFF + N_TOKENS*4u)

// ---------------------------------------------------------------------------
// K1: codebooks fp32 -> bf16, ||c||^2, zero histogram.
// ---------------------------------------------------------------------------
__global__ __launch_bounds__(256) void k_prep(const float* __restrict__ cbf,
                                              unsigned short* __restrict__ cbh,
                                              float* __restrict__ cnorm,
                                              int* __restrict__ hist) {
    const int tid = blockIdx.x * 256 + threadIdx.x;
    if (tid < N_CODES) hist[tid] = 0;

    const int w = threadIdx.x >> 6;
    const int lane = threadIdx.x & 63;
    const int row = blockIdx.x * 4 + w;

    const float4 v = ((const float4*)(cbf + (size_t)row * DIM))[lane];
    float sq = v.x * v.x + v.y * v.y + v.z * v.z + v.w * v.w;

    ushort4 u;
    u.x = __builtin_bit_cast(unsigned short, (__bf16)v.x);
    u.y = __builtin_bit_cast(unsigned short, (__bf16)v.y);
    u.z = __builtin_bit_cast(unsigned short, (__bf16)v.z);
    u.w = __builtin_bit_cast(unsigned short, (__bf16)v.w);
    ((ushort4*)(cbh + (size_t)row * DIM))[lane] = u;

    #pragma unroll
    for (int d = 1; d < 64; d <<= 1) sq += __shfl_xor(sq, d);
    if (lane == 0) cnorm[row] = sq;
}

// ---------------------------------------------------------------------------
// K2: fused distance-matmul + argmin, v3.
//  - 128 tokens/block, grid=256 (1 block/CU; LDS padded >80KB to force
//    exclusive residency). Wave w owns codes [16w,16w+16) x all 128 tokens.
//  - A (128 tok x 256 d, bf16) in registers: 8 mf x 8 kc frags = 256 VGPR.
//    Loaded once via LDS round-trip (coalesced global, 1x X traffic).
//  - ||c||^2 folded into MFMA C-operand: acc = x.c - cn/2; argmax(acc).
//    cn prefetched one chunk ahead -> NO mid-chunk vmcnt drain.
//  - B staged via global_load_lds 16B, double-buffered, per-wave-private
//    regions, XOR-swizzled at 16B granularity; no block barrier in loop.
// ---------------------------------------------------------------------------
__global__ __launch_bounds__(256, 1) void k_argmin(const float* __restrict__ X,
                                                   const unsigned short* __restrict__ cbh,
                                                   const float* __restrict__ cnorm,
                                                   int* __restrict__ idxout) {
    __shared__ __attribute__((aligned(16))) char Bs[2][40960];  // 32KB used/buf + pad
    __shared__ float redv[4][128];
    __shared__ int   redi[4][128];

    const int tid  = threadIdx.x;
    const int w    = tid >> 6;
    const int lane = tid & 63;
    const int lr   = lane & 15;
    const int lq   = lane >> 4;
    const int r0   = blockIdx.x * 128;
    const int mycol = w * 16 + lr;

    // ---- stage A: wave w loads tokens [32w,32w+32) f32, converts to bf16,
    //      token row stride 544B in LDS (breaks the 512B power-of-2 stride) ----
    {
        const float4* Xf4 = (const float4*)(X + (size_t)(r0 + 32 * w) * DIM);
        for (int i = 0; i < 32; ++i) {
            const float4 v = Xf4[i * 64 + lane];
            ushort4 u;
            u.x = __builtin_bit_cast(unsigned short, (__bf16)v.x);
            u.y = __builtin_bit_cast(unsigned short, (__bf16)v.y);
            u.z = __builtin_bit_cast(unsigned short, (__bf16)v.z);
            u.w = __builtin_bit_cast(unsigned short, (__bf16)v.w);
            *(ushort4*)(&Bs[0][0] + (32 * w + i) * 544 + lane * 8) = u;
        }
    }
    __syncthreads();

    bf16x8 A[8][8];
    #pragma unroll
    for (int mf = 0; mf < 8; ++mf)
        #pragma unroll
        for (int kc = 0; kc < 8; ++kc)
            A[mf][kc] = *(const bf16x8*)(&Bs[0][0] + (mf * 16 + lr) * 544 + kc * 64 + lq * 16);
    __syncthreads();   // A reads done before chunk staging overwrites Bs

    // ---- staging source offsets (bytes within a 32KB chunk) ----
    const int half = lane >> 5, l5 = lane & 31;
    int srcoff[8];
    #pragma unroll
    for (int s = 0; s < 8; ++s) {
        const int c = w * 16 + 2 * s + half;  // code row this lane helps stage
        const int j = (l5 - c) & 31;          // source 16B-chunk landing in slot l5
        srcoff[s] = c * 512 + j * 16;
    }
    const char* cbb = (const char*)cbh;

    // ---- chunk 0 staging + cnorm prefetch ----
    #pragma unroll
    for (int s = 0; s < 8; ++s)
        __builtin_amdgcn_global_load_lds(
            (const __attribute__((address_space(1))) unsigned int*)(cbb + srcoff[s]),
            (__attribute__((address_space(3))) unsigned int*)(&Bs[0][w * 8192 + s * 1024]),
            16, 0, 0);
    float cn_next = cnorm[mycol];

    float maxv[32];
    int   maxi[32];
    #pragma unroll
    for (int i = 0; i < 32; ++i) { maxv[i] = -3.4e38f; maxi[i] = 0; }

    for (int cc = 0; cc < 128; ++cc) {
        // own staging for chunk cc + cn prefetch landed (issued a full phase ago)
        asm volatile("s_waitcnt vmcnt(0)" ::: "memory");
        const float cn = cn_next;

        if (cc + 1 < 128) {
            const char* src = cbb + (size_t)(cc + 1) * 32768;
            char* dst = &Bs[(cc + 1) & 1][w * 8192];
            #pragma unroll
            for (int s = 0; s < 8; ++s)
                __builtin_amdgcn_global_load_lds(
                    (const __attribute__((address_space(1))) unsigned int*)(src + srcoff[s]),
                    (__attribute__((address_space(3))) unsigned int*)(dst + s * 1024),
                    16, 0, 0);
            cn_next = cnorm[(cc + 1) * 64 + mycol];
        }

        const float cinit = -0.5f * cn;
        f32x4 acc[8];
        #pragma unroll
        for (int mf = 0; mf < 8; ++mf) {
            acc[mf][0] = cinit; acc[mf][1] = cinit; acc[mf][2] = cinit; acc[mf][3] = cinit;
        }

        const char* bp = &Bs[cc & 1][0] + mycol * 512;
        #pragma unroll
        for (int kc = 0; kc < 8; ++kc) {
            const bf16x8 b = *(const bf16x8*)(bp + (((kc * 4 + lq + mycol) & 31) << 4));
            #pragma unroll
            for (int mf = 0; mf < 8; ++mf)
                acc[mf] = __builtin_amdgcn_mfma_f32_16x16x32_bf16(A[mf][kc], b, acc[mf], 0, 0, 0);
        }

        const int col = cc * 64 + mycol;
        #pragma unroll
        for (int mf = 0; mf < 8; ++mf)
            #pragma unroll
            for (int r = 0; r < 4; ++r) {
                const float v = acc[mf][r];
                const int j = mf * 4 + r;
                if (v > maxv[j]) { maxv[j] = v; maxi[j] = col; }
            }
    }

    // ---- reduce across the 16 lanes (lr) sharing each token row ----
    #pragma unroll
    for (int mf = 0; mf < 8; ++mf)
        #pragma unroll
        for (int r = 0; r < 4; ++r) {
            float v = maxv[mf * 4 + r]; int ix = maxi[mf * 4 + r];
            #pragma unroll
            for (int d = 1; d <= 8; d <<= 1) {
                const float ov = __shfl_xor(v, d);
                const int   oi = __shfl_xor(ix, d);
                if (ov > v || (ov == v && oi < ix)) { v = ov; ix = oi; }
            }
            if (lr == 0) {
                const int row = mf * 16 + lq * 4 + r;
                redv[w][row] = v; redi[w][row] = ix;
            }
        }
    __syncthreads();

    // ---- reduce across the 4 waves (different code windows, same tokens) ----
    if (tid < 128) {
        float v = redv[0][tid]; int ix = redi[0][tid];
        #pragma unroll
        for (int ww = 1; ww < 4; ++ww) {
            const float ov = redv[ww][tid]; const int oi = redi[ww][tid];
            if (ov > v || (ov == v && oi < ix)) { v = ov; ix = oi; }
        }
        idxout[r0 + tid] = ix;
    }
}

// ---------------------------------------------------------------------------
// K3: exact fp32 epilogue: r_norm, n_norm, output write, histogram.
// ---------------------------------------------------------------------------
__global__ __launch_bounds__(256) void k_quant(const float* __restrict__ X,
                                               const float* __restrict__ R,
                                               const float* __restrict__ C,
                                               const int* __restrict__ idx,
                                               float* __restrict__ out,
                                               int* __restrict__ hist) {
    const int w = threadIdx.x >> 6;
    const int lane = threadIdx.x & 63;
    const int tok = blockIdx.x * 4 + w;
    const int k = idx[tok];

    const float4 x = ((const float4*)(X + (size_t)tok * DIM))[lane];
    const float4 r = ((const float4*)(R + (size_t)tok * DIM))[lane];
    const float4 c = ((const float4*)(C + (size_t)k * DIM))[lane];

    const float d0 = x.x - c.x, d1 = x.y - c.y, d2 = x.z - c.z, d3 = x.w - c.w;
    float r2 = d0 * d0 + d1 * d1 + d2 * d2 + d3 * d3;
    float n2 = r.x * r.x + r.y * r.y + r.z * r.z + r.w * r.w;
    #pragma unroll
    for (int d = 1; d < 64; d <<= 1) {
        r2 += __shfl_xor(r2, d);
        n2 += __shfl_xor(n2, d);
    }
    const float s = sqrtf(r2) / (sqrtf(n2) + EPSF);

    float4 o;
    o.x = fmaf(s, r.x, x.x);
    o.y = fmaf(s, r.y, x.y);
    o.z = fmaf(s, r.z, x.z);
    o.w = fmaf(s, r.w, x.w);
    ((float4*)(out + (size_t)tok * DIM))[lane] = o;

    if (lane == 0) atomicAdd(&hist[k], 1);
}

// ---------------------------------------------------------------------------
// K4: perplexity + num_unique from histogram. single block.
// ---------------------------------------------------------------------------
__global__ __launch_bounds__(256) void k_stats(const int* __restrict__ hist,
                                               float* __restrict__ outs) {
    float s = 0.f; int u = 0;
    for (int b = threadIdx.x; b < N_CODES; b += 256) {
        const float c = (float)hist[b];
        if (c > 0.f) ++u;
        const float p = c * (1.f / (float)N_TOKENS);
        s += p * logf(p + EPSF);
    }
    #pragma unroll
    for (int d = 1; d < 64; d <<= 1) {
        s += __shfl_xor(s, d);
        u += __shfl_xor(u, d);
    }
    __shared__ float ss[4];
    __shared__ int   su[4];
    const int w = threadIdx.x >> 6, lane = threadIdx.x & 63;
    if (lane == 0) { ss[w] = s; su[w] = u; }
    __syncthreads();
    if (threadIdx.x == 0) {
        const float st = ss[0] + ss[1] + ss[2] + ss[3];
        const int ut = su[0] + su[1] + su[2] + su[3];
        outs[0] = expf(-st);       // perplexity
        outs[1] = (float)ut;       // num_unique_indices
    }
}

// ---------------------------------------------------------------------------
extern "C" void kernel_launch(void* const* d_in, const int* in_sizes, int n_in,
                              void* d_out, int out_size, void* d_ws, size_t ws_size,
                              hipStream_t stream) {
    const float* X = (const float*)d_in[0];  // input_data (32768,256)
    const float* R = (const float*)d_in[1];  // rand       (32768,256)
    const float* C = (const float*)d_in[2];  // codebooks  (8192,256)
    float* out = (float*)d_out;

    char* ws = (char*)d_ws;
    unsigned short* cbh = (unsigned short*)ws;             // bf16 codebooks
    float* cnorm = (float*)(ws + WS_CNORM_OFF);
    int*   idx   = (int*)(ws + WS_IDX_OFF);
    int*   hist  = (int*)(ws + WS_HIST_OFF);

    k_prep  <<<N_CODES / 4,   256, 0, stream>>>(C, cbh, cnorm, hist);
    k_argmin<<<N_TOKENS / 128, 256, 0, stream>>>(X, cbh, cnorm, idx);
    k_quant <<<N_TOKENS / 4,  256, 0, stream>>>(X, R, C, idx, out, hist);
    k_stats <<<1, 256, 0, stream>>>(hist, out + (size_t)N_TOKENS * DIM);
}

// Round 4
// 262.383 us; speedup vs baseline: 1.2648x; 1.2648x over previous
//
#include <hip/hip_runtime.h>
#include <stdint.h>

#define N_TOKENS 32768
#define N_CODES  8192
#define DIM      256
#define EPSF     1e-8f

typedef __bf16 bf16x8 __attribute__((ext_vector_type(8)));
typedef float  f32x4  __attribute__((ext_vector_type(4)));

// ---------------------------------------------------------------------------
// ws layout: [bf16 codebooks 4MiB][cnorm f32 32KiB][maxv f32 128KiB][hist i32 32KiB]
// ---------------------------------------------------------------------------
#define WS_CNORM_OFF  (4u*1024u*1024u)
#define WS_MAXV_OFF   (WS_CNORM_OFF + N_CODES*4u)
#define WS_HIST_OFF   (WS_MAXV_OFF + N_TOKENS*4u)

// ---------------------------------------------------------------------------
// K1: codebooks fp32 -> bf16, ||c||^2, zero histogram.
// ---------------------------------------------------------------------------
__global__ __launch_bounds__(256) void k_prep(const float* __restrict__ cbf,
                                              unsigned short* __restrict__ cbh,
                                              float* __restrict__ cnorm,
                                              int* __restrict__ hist) {
    const int tid = blockIdx.x * 256 + threadIdx.x;
    if (tid < N_CODES) hist[tid] = 0;

    const int w = threadIdx.x >> 6;
    const int lane = threadIdx.x & 63;
    const int row = blockIdx.x * 4 + w;

    const float4 v = ((const float4*)(cbf + (size_t)row * DIM))[lane];
    float sq = v.x * v.x + v.y * v.y + v.z * v.z + v.w * v.w;

    ushort4 u;
    u.x = __builtin_bit_cast(unsigned short, (__bf16)v.x);
    u.y = __builtin_bit_cast(unsigned short, (__bf16)v.y);
    u.z = __builtin_bit_cast(unsigned short, (__bf16)v.z);
    u.w = __builtin_bit_cast(unsigned short, (__bf16)v.w);
    ((ushort4*)(cbh + (size_t)row * DIM))[lane] = u;

    #pragma unroll
    for (int d = 1; d < 64; d <<= 1) sq += __shfl_xor(sq, d);
    if (lane == 0) cnorm[row] = sq;
}

// ---------------------------------------------------------------------------
// K2: fused distance-matmul + argmax(x.c - cn/2), v4.
//  - 64 tokens/block, 512 blocks, 2 blocks/CU (2 waves/SIMD overlap — the
//    r3 regression showed 1 wave/SIMD exposes all VALU+wait serially).
//  - A (64 tok x 256 d bf16) in registers (128 VGPR), loaded via LDS.
//  - ||c||^2 folded into MFMA C-operand init; cnorm chunk rides the
//    global_load_lds queue (width-4 DMA) -> single top-of-chunk vmcnt(0),
//    for loads issued one full compute phase earlier. No block barrier.
//  - B double-buffered, per-wave-private regions, 16B XOR swizzle.
//  - Emits maxv[token] + histogram atomics; no idx round-trip needed.
// ---------------------------------------------------------------------------
__global__ __launch_bounds__(256, 2) void k_argmin(const float* __restrict__ X,
                                                   const unsigned short* __restrict__ cbh,
                                                   const float* __restrict__ cnorm,
                                                   float* __restrict__ maxvOut,
                                                   int* __restrict__ hist) {
    __shared__ __attribute__((aligned(16))) char Bs[2][32768];
    __shared__ __attribute__((aligned(16))) float cnS[2][4][64];
    __shared__ float redv[4][64];
    __shared__ int   redi[4][64];

    const int tid  = threadIdx.x;
    const int w    = tid >> 6;
    const int lane = tid & 63;
    const int lr   = lane & 15;
    const int lq   = lane >> 4;
    const int r0   = blockIdx.x * 64;
    const int mycol = w * 16 + lr;

    // ---- stage A: wave w loads tokens [16w,16w+16), row stride 544B ----
    {
        const float4* Xf4 = (const float4*)(X + (size_t)(r0 + 16 * w) * DIM);
        #pragma unroll
        for (int i = 0; i < 16; ++i) {
            const float4 v = Xf4[i * 64 + lane];
            ushort4 u;
            u.x = __builtin_bit_cast(unsigned short, (__bf16)v.x);
            u.y = __builtin_bit_cast(unsigned short, (__bf16)v.y);
            u.z = __builtin_bit_cast(unsigned short, (__bf16)v.z);
            u.w = __builtin_bit_cast(unsigned short, (__bf16)v.w);
            *(ushort4*)(&Bs[0][0] + (16 * w + i) * 544 + lane * 8) = u;
        }
    }
    __syncthreads();

    bf16x8 A[4][8];
    #pragma unroll
    for (int mf = 0; mf < 4; ++mf)
        #pragma unroll
        for (int kc = 0; kc < 8; ++kc)
            A[mf][kc] = *(const bf16x8*)(&Bs[0][0] + (mf * 16 + lr) * 544 + kc * 64 + lq * 16);
    __syncthreads();   // A reads done before chunk-0 staging overwrites Bs

    // ---- staging source offsets (bytes within a 32KB chunk) ----
    const int half = lane >> 5, l5 = lane & 31;
    int srcoff[8];
    #pragma unroll
    for (int s = 0; s < 8; ++s) {
        const int c = w * 16 + 2 * s + half;  // code row this lane helps stage
        const int j = (l5 - c) & 31;          // source 16B-chunk landing in slot l5
        srcoff[s] = c * 512 + j * 16;
    }
    const char* cbb = (const char*)cbh;

    // ---- chunk 0 staging (B + cnorm) ----
    #pragma unroll
    for (int s = 0; s < 8; ++s)
        __builtin_amdgcn_global_load_lds(
            (const __attribute__((address_space(1))) unsigned int*)(cbb + srcoff[s]),
            (__attribute__((address_space(3))) unsigned int*)(&Bs[0][w * 8192 + s * 1024]),
            16, 0, 0);
    __builtin_amdgcn_global_load_lds(
        (const __attribute__((address_space(1))) unsigned int*)(cnorm + lane),
        (__attribute__((address_space(3))) unsigned int*)(&cnS[0][w][0]),
        4, 0, 0);

    float maxv[16];
    int   maxi[16];
    #pragma unroll
    for (int i = 0; i < 16; ++i) { maxv[i] = -3.4e38f; maxi[i] = 0; }

    for (int cc = 0; cc < 128; ++cc) {
        // loads for chunk cc were issued one full compute phase ago
        asm volatile("s_waitcnt vmcnt(0)" ::: "memory");

        if (cc + 1 < 128) {
            const char* src = cbb + (size_t)(cc + 1) * 32768;
            char* dst = &Bs[(cc + 1) & 1][w * 8192];
            #pragma unroll
            for (int s = 0; s < 8; ++s)
                __builtin_amdgcn_global_load_lds(
                    (const __attribute__((address_space(1))) unsigned int*)(src + srcoff[s]),
                    (__attribute__((address_space(3))) unsigned int*)(dst + s * 1024),
                    16, 0, 0);
            __builtin_amdgcn_global_load_lds(
                (const __attribute__((address_space(1))) unsigned int*)(cnorm + (cc + 1) * 64 + lane),
                (__attribute__((address_space(3))) unsigned int*)(&cnS[(cc + 1) & 1][w][0]),
                4, 0, 0);
        }

        const float cinit = -0.5f * cnS[cc & 1][w][mycol];
        f32x4 acc[4];
        #pragma unroll
        for (int mf = 0; mf < 4; ++mf) {
            acc[mf][0] = cinit; acc[mf][1] = cinit; acc[mf][2] = cinit; acc[mf][3] = cinit;
        }

        const char* bp = &Bs[cc & 1][0] + mycol * 512;
        #pragma unroll
        for (int kc = 0; kc < 8; ++kc) {
            const bf16x8 b = *(const bf16x8*)(bp + (((kc * 4 + lq + mycol) & 31) << 4));
            #pragma unroll
            for (int mf = 0; mf < 4; ++mf)
                acc[mf] = __builtin_amdgcn_mfma_f32_16x16x32_bf16(A[mf][kc], b, acc[mf], 0, 0, 0);
        }

        const int col = cc * 64 + mycol;
        #pragma unroll
        for (int mf = 0; mf < 4; ++mf)
            #pragma unroll
            for (int r = 0; r < 4; ++r) {
                const float v = acc[mf][r];
                const int j = mf * 4 + r;
                if (v > maxv[j]) { maxv[j] = v; maxi[j] = col; }
            }
    }

    // ---- reduce across the 16 lanes (lr) sharing each token row ----
    #pragma unroll
    for (int mf = 0; mf < 4; ++mf)
        #pragma unroll
        for (int r = 0; r < 4; ++r) {
            float v = maxv[mf * 4 + r]; int ix = maxi[mf * 4 + r];
            #pragma unroll
            for (int d = 1; d <= 8; d <<= 1) {
                const float ov = __shfl_xor(v, d);
                const int   oi = __shfl_xor(ix, d);
                if (ov > v || (ov == v && oi < ix)) { v = ov; ix = oi; }
            }
            if (lr == 0) {
                const int row = mf * 16 + lq * 4 + r;
                redv[w][row] = v; redi[w][row] = ix;
            }
        }
    __syncthreads();

    // ---- reduce across the 4 waves; emit maxv + histogram ----
    if (tid < 64) {
        float v = redv[0][tid]; int ix = redi[0][tid];
        #pragma unroll
        for (int ww = 1; ww < 4; ++ww) {
            const float ov = redv[ww][tid]; const int oi = redi[ww][tid];
            if (ov > v || (ov == v && oi < ix)) { v = ov; ix = oi; }
        }
        maxvOut[r0 + tid] = v;
        atomicAdd(&hist[ix], 1);
    }
}

// ---------------------------------------------------------------------------
// K3: streaming epilogue. r_norm^2 = ||x||^2 - 2*maxv (the min-d2 identity);
// no codebook gather, no idx. out = x + (r_norm/(n_norm+eps)) * rand.
// ---------------------------------------------------------------------------
__global__ __launch_bounds__(256) void k_quant(const float* __restrict__ X,
                                               const float* __restrict__ R,
                                               const float* __restrict__ Mv,
                                               float* __restrict__ out) {
    const int w = threadIdx.x >> 6;
    const int lane = threadIdx.x & 63;
    const int tok = blockIdx.x * 4 + w;

    const float4 x = ((const float4*)(X + (size_t)tok * DIM))[lane];
    const float4 r = ((const float4*)(R + (size_t)tok * DIM))[lane];

    float x2 = x.x * x.x + x.y * x.y + x.z * x.z + x.w * x.w;
    float n2 = r.x * r.x + r.y * r.y + r.z * r.z + r.w * r.w;
    #pragma unroll
    for (int d = 1; d < 64; d <<= 1) {
        x2 += __shfl_xor(x2, d);
        n2 += __shfl_xor(n2, d);
    }
    const float mv = Mv[tok];
    const float d2 = fmaxf(fmaf(-2.f, mv, x2), 0.f);
    const float s = sqrtf(d2) / (sqrtf(n2) + EPSF);

    float4 o;
    o.x = fmaf(s, r.x, x.x);
    o.y = fmaf(s, r.y, x.y);
    o.z = fmaf(s, r.z, x.z);
    o.w = fmaf(s, r.w, x.w);
    ((float4*)(out + (size_t)tok * DIM))[lane] = o;
}

// ---------------------------------------------------------------------------
// K4: perplexity + num_unique from histogram. single block.
// ---------------------------------------------------------------------------
__global__ __launch_bounds__(256) void k_stats(const int* __restrict__ hist,
                                               float* __restrict__ outs) {
    float s = 0.f; int u = 0;
    for (int b = threadIdx.x; b < N_CODES; b += 256) {
        const float c = (float)hist[b];
        if (c > 0.f) ++u;
        const float p = c * (1.f / (float)N_TOKENS);
        s += p * logf(p + EPSF);
    }
    #pragma unroll
    for (int d = 1; d < 64; d <<= 1) {
        s += __shfl_xor(s, d);
        u += __shfl_xor(u, d);
    }
    __shared__ float ss[4];
    __shared__ int   su[4];
    const int w = threadIdx.x >> 6, lane = threadIdx.x & 63;
    if (lane == 0) { ss[w] = s; su[w] = u; }
    __syncthreads();
    if (threadIdx.x == 0) {
        const float st = ss[0] + ss[1] + ss[2] + ss[3];
        const int ut = su[0] + su[1] + su[2] + su[3];
        outs[0] = expf(-st);       // perplexity
        outs[1] = (float)ut;       // num_unique_indices
    }
}

// ---------------------------------------------------------------------------
extern "C" void kernel_launch(void* const* d_in, const int* in_sizes, int n_in,
                              void* d_out, int out_size, void* d_ws, size_t ws_size,
                              hipStream_t stream) {
    const float* X = (const float*)d_in[0];  // input_data (32768,256)
    const float* R = (const float*)d_in[1];  // rand       (32768,256)
    const float* C = (const float*)d_in[2];  // codebooks  (8192,256)
    float* out = (float*)d_out;

    char* ws = (char*)d_ws;
    unsigned short* cbh = (unsigned short*)ws;             // bf16 codebooks
    float* cnorm = (float*)(ws + WS_CNORM_OFF);
    float* maxv  = (float*)(ws + WS_MAXV_OFF);
    int*   hist  = (int*)(ws + WS_HIST_OFF);

    k_prep  <<<N_CODES / 4,  256, 0, stream>>>(C, cbh, cnorm, hist);
    k_argmin<<<N_TOKENS / 64, 256, 0, stream>>>(X, cbh, cnorm, maxv, hist);
    k_quant <<<N_TOKENS / 4, 256, 0, stream>>>(X, R, maxv, out);
    k_stats <<<1, 256, 0, stream>>>(hist, out + (size_t)N_TOKENS * DIM);
}

// Round 6
// 244.771 us; speedup vs baseline: 1.3558x; 1.0720x over previous
//
#include <hip/hip_runtime.h>
#include <stdint.h>

#define N_TOKENS 32768
#define N_CODES  8192
#define DIM      256
#define EPSF     1e-8f

typedef __bf16 bf16x8 __attribute__((ext_vector_type(8)));
typedef float  f32x4  __attribute__((ext_vector_type(4)));

// ws layout: [bf16 codebooks 4MiB][cnorm f32 32KiB][hist i32 32KiB]
#define WS_CNORM_OFF  (4u*1024u*1024u)
#define WS_HIST_OFF   (WS_CNORM_OFF + N_CODES*4u)

// ---------------------------------------------------------------------------
// K1: codebooks fp32 -> bf16, ||c||^2, zero histogram.
// ---------------------------------------------------------------------------
__global__ __launch_bounds__(256) void k_prep(const float* __restrict__ cbf,
                                              unsigned short* __restrict__ cbh,
                                              float* __restrict__ cnorm,
                                              int* __restrict__ hist) {
    const int tid = blockIdx.x * 256 + threadIdx.x;
    if (tid < N_CODES) hist[tid] = 0;

    const int w = threadIdx.x >> 6;
    const int lane = threadIdx.x & 63;
    const int row = blockIdx.x * 4 + w;

    const float4 v = ((const float4*)(cbf + (size_t)row * DIM))[lane];
    float sq = v.x * v.x + v.y * v.y + v.z * v.z + v.w * v.w;

    ushort4 u;
    u.x = __builtin_bit_cast(unsigned short, (__bf16)v.x);
    u.y = __builtin_bit_cast(unsigned short, (__bf16)v.y);
    u.z = __builtin_bit_cast(unsigned short, (__bf16)v.z);
    u.w = __builtin_bit_cast(unsigned short, (__bf16)v.w);
    ((ushort4*)(cbh + (size_t)row * DIM))[lane] = u;

    #pragma unroll
    for (int d = 1; d < 64; d <<= 1) sq += __shfl_xor(sq, d);
    if (lane == 0) cnorm[row] = sq;
}

// ---------------------------------------------------------------------------
// K2: fused distance-matmul + argmax(x.c - cn/2) + quant epilogue, v5b.
//  - 512 thr (8 waves), 128 tokens/block, grid=256, 1 block/CU (LDS 85KB).
//    Wave (th=w>>2, wc=w&3): codes [16wc,16wc+16) x tokens [64th,64th+64).
//    2 waves/SIMD overlap kept; chunk fetched ONCE per CU (halves L2+LDS
//    traffic vs r4's 2 blocks/CU).
//  - Chunk staged cooperatively (wave w stages codes [8w,8w+8)); cross-wave
//    visibility via ONE barrier per chunk at loop BOTTOM: DMAs issued at loop
//    top get the full compute phase to land -> pre-barrier vmcnt drain ~free.
//  - ||c||^2 in MFMA C-init; cnorm rides the DMA queue (wave 0, width-4).
//  - Quant epilogue fused: maxv stays in LDS; re-read X,R, write out here.
//  - NOTE: no pointer arrays over __shared__ (gfx950 rejects the
//    addrspacecast initializer) — buffer select is done on byte offsets.
// ---------------------------------------------------------------------------
__global__ __launch_bounds__(512, 2) void k_argmin(const float* __restrict__ X,
                                                   const float* __restrict__ R,
                                                   const unsigned short* __restrict__ cbh,
                                                   const float* __restrict__ cnorm,
                                                   float* __restrict__ out,
                                                   int* __restrict__ hist) {
    // layout: [0,32768) Bs0 | [32768,65536) Bs1 | [65536,66048) cnS[2][64]
    //         [66048,68096) redv[8][64] | [68096,70144) redi[8][64]
    //         [70144,70656) maxvS[128]
    // A-stage (128 tok x 544B = 69632B) transiently overlays [0,69632).
    __shared__ __attribute__((aligned(16))) char smem[87040];
    float* cnS   = (float*)(smem + 65536);
    float* redv  = (float*)(smem + 66048);
    int*   redi  = (int*)(smem + 68096);
    float* maxvS = (float*)(smem + 70144);

    const int tid  = threadIdx.x;
    const int w    = tid >> 6;
    const int lane = tid & 63;
    const int lr   = lane & 15;
    const int lq   = lane >> 4;
    const int th   = w >> 2;          // token half
    const int wc   = w & 3;           // code quarter
    const int r0   = blockIdx.x * 128;
    const int mycol = wc * 16 + lr;

    // ---- A-stage: wave w loads tokens [16w,16w+16), row stride 544B ----
    {
        const float4* Xf4 = (const float4*)(X + (size_t)(r0 + 16 * w) * DIM);
        #pragma unroll
        for (int i = 0; i < 16; ++i) {
            const float4 v = Xf4[i * 64 + lane];
            ushort4 u;
            u.x = __builtin_bit_cast(unsigned short, (__bf16)v.x);
            u.y = __builtin_bit_cast(unsigned short, (__bf16)v.y);
            u.z = __builtin_bit_cast(unsigned short, (__bf16)v.z);
            u.w = __builtin_bit_cast(unsigned short, (__bf16)v.w);
            *(ushort4*)(smem + (16 * w + i) * 544 + lane * 8) = u;
        }
    }
    __syncthreads();

    bf16x8 A[4][8];
    #pragma unroll
    for (int mf = 0; mf < 4; ++mf)
        #pragma unroll
        for (int kc = 0; kc < 8; ++kc)
            A[mf][kc] = *(const bf16x8*)(smem + (64 * th + mf * 16 + lr) * 544 + kc * 64 + lq * 16);
    __syncthreads();   // A reads done before chunk-0 staging overwrites smem

    // ---- staging source offsets: wave w stages codes [8w, 8w+8), 4 DMAs ----
    const int half = lane >> 5, l5 = lane & 31;
    int srcoff[4];
    #pragma unroll
    for (int s = 0; s < 4; ++s) {
        const int c = 8 * w + 2 * s + half;   // code row this lane helps stage
        const int j = (l5 - c) & 31;          // source 16B-chunk landing in slot l5
        srcoff[s] = c * 512 + j * 16;
    }
    const char* cbb = (const char*)cbh;

    // ---- chunk 0 staging (B + cnorm) ----
    #pragma unroll
    for (int s = 0; s < 4; ++s)
        __builtin_amdgcn_global_load_lds(
            (const __attribute__((address_space(1))) unsigned int*)(cbb + srcoff[s]),
            (__attribute__((address_space(3))) unsigned int*)(smem + w * 4096 + s * 1024),
            16, 0, 0);
    if (w == 0)
        __builtin_amdgcn_global_load_lds(
            (const __attribute__((address_space(1))) unsigned int*)(cnorm + lane),
            (__attribute__((address_space(3))) unsigned int*)(cnS),
            4, 0, 0);
    __syncthreads();   // compiler drains vmcnt before the barrier

    float maxv[16];
    int   maxi[16];
    #pragma unroll
    for (int i = 0; i < 16; ++i) { maxv[i] = -3.4e38f; maxi[i] = 0; }

    for (int cc = 0; cc < 128; ++cc) {
        const int cur = (cc & 1) * 32768;
        // issue next chunk's staging first: full compute phase to land
        if (cc + 1 < 128) {
            const int nxt = ((cc + 1) & 1) * 32768;
            const char* src = cbb + (size_t)(cc + 1) * 32768;
            #pragma unroll
            for (int s = 0; s < 4; ++s)
                __builtin_amdgcn_global_load_lds(
                    (const __attribute__((address_space(1))) unsigned int*)(src + srcoff[s]),
                    (__attribute__((address_space(3))) unsigned int*)(smem + nxt + w * 4096 + s * 1024),
                    16, 0, 0);
            if (w == 0)
                __builtin_amdgcn_global_load_lds(
                    (const __attribute__((address_space(1))) unsigned int*)(cnorm + (cc + 1) * 64 + lane),
                    (__attribute__((address_space(3))) unsigned int*)(cnS + ((cc + 1) & 1) * 64),
                    4, 0, 0);
        }

        const float cinit = -0.5f * cnS[(cc & 1) * 64 + mycol];
        f32x4 acc[4];
        #pragma unroll
        for (int mf = 0; mf < 4; ++mf) {
            acc[mf][0] = cinit; acc[mf][1] = cinit; acc[mf][2] = cinit; acc[mf][3] = cinit;
        }

        #pragma unroll
        for (int kc = 0; kc < 8; ++kc) {
            const bf16x8 b = *(const bf16x8*)(smem + cur + mycol * 512 +
                                              (((kc * 4 + lq + mycol) & 31) << 4));
            #pragma unroll
            for (int mf = 0; mf < 4; ++mf)
                acc[mf] = __builtin_amdgcn_mfma_f32_16x16x32_bf16(A[mf][kc], b, acc[mf], 0, 0, 0);
        }

        const int col = cc * 64 + mycol;
        #pragma unroll
        for (int mf = 0; mf < 4; ++mf)
            #pragma unroll
            for (int r = 0; r < 4; ++r) {
                const float v = acc[mf][r];
                const int j = mf * 4 + r;
                if (v > maxv[j]) { maxv[j] = v; maxi[j] = col; }
            }

        // all waves' DMAs (issued at top) complete + all reads of buffer cur
        // retire before next iteration's staging overwrites the other buffer.
        __syncthreads();
    }

    // ---- reduce across the 16 lanes (lr) sharing each token row ----
    #pragma unroll
    for (int mf = 0; mf < 4; ++mf)
        #pragma unroll
        for (int r = 0; r < 4; ++r) {
            float v = maxv[mf * 4 + r]; int ix = maxi[mf * 4 + r];
            #pragma unroll
            for (int d = 1; d <= 8; d <<= 1) {
                const float ov = __shfl_xor(v, d);
                const int   oi = __shfl_xor(ix, d);
                if (ov > v || (ov == v && oi < ix)) { v = ov; ix = oi; }
            }
            if (lr == 0) {
                const int row = mf * 16 + lq * 4 + r;   // token row within half
                redv[w * 64 + row] = v; redi[w * 64 + row] = ix;
            }
        }
    __syncthreads();

    // ---- combine the 4 code-quarter waves per token; hist + maxvS ----
    if (tid < 128) {
        const int t = tid, tth = t >> 6, tl = t & 63;
        float v = redv[(4 * tth) * 64 + tl]; int ix = redi[(4 * tth) * 64 + tl];
        #pragma unroll
        for (int ww = 1; ww < 4; ++ww) {
            const float ov = redv[(4 * tth + ww) * 64 + tl];
            const int   oi = redi[(4 * tth + ww) * 64 + tl];
            if (ov > v || (ov == v && oi < ix)) { v = ov; ix = oi; }
        }
        maxvS[t] = v;
        atomicAdd(&hist[ix], 1);
    }
    __syncthreads();

    // ---- fused quant epilogue: wave w handles tokens [16w, 16w+16) ----
    for (int i = 0; i < 16; ++i) {
        const int tl = 16 * w + i;
        const int tok = r0 + tl;
        const float4 x = ((const float4*)(X + (size_t)tok * DIM))[lane];
        const float4 r = ((const float4*)(R + (size_t)tok * DIM))[lane];

        float x2 = x.x * x.x + x.y * x.y + x.z * x.z + x.w * x.w;
        float n2 = r.x * r.x + r.y * r.y + r.z * r.z + r.w * r.w;
        #pragma unroll
        for (int d = 1; d < 64; d <<= 1) {
            x2 += __shfl_xor(x2, d);
            n2 += __shfl_xor(n2, d);
        }
        const float mv = maxvS[tl];
        const float d2 = fmaxf(fmaf(-2.f, mv, x2), 0.f);
        const float s = sqrtf(d2) / (sqrtf(n2) + EPSF);

        float4 o;
        o.x = fmaf(s, r.x, x.x);
        o.y = fmaf(s, r.y, x.y);
        o.z = fmaf(s, r.z, x.z);
        o.w = fmaf(s, r.w, x.w);
        ((float4*)(out + (size_t)tok * DIM))[lane] = o;
    }
}

// ---------------------------------------------------------------------------
// K3: perplexity + num_unique from histogram. single block, 1024 thr.
// ---------------------------------------------------------------------------
__global__ __launch_bounds__(1024) void k_stats(const int* __restrict__ hist,
                                                float* __restrict__ outs) {
    float s = 0.f; int u = 0;
    for (int b = threadIdx.x; b < N_CODES; b += 1024) {
        const float c = (float)hist[b];
        if (c > 0.f) ++u;
        const float p = c * (1.f / (float)N_TOKENS);
        s += p * logf(p + EPSF);
    }
    #pragma unroll
    for (int d = 1; d < 64; d <<= 1) {
        s += __shfl_xor(s, d);
        u += __shfl_xor(u, d);
    }
    __shared__ float ss[16];
    __shared__ int   su[16];
    const int w = threadIdx.x >> 6, lane = threadIdx.x & 63;
    if (lane == 0) { ss[w] = s; su[w] = u; }
    __syncthreads();
    if (threadIdx.x == 0) {
        float st = 0.f; int ut = 0;
        #pragma unroll
        for (int i = 0; i < 16; ++i) { st += ss[i]; ut += su[i]; }
        outs[0] = expf(-st);       // perplexity
        outs[1] = (float)ut;       // num_unique_indices
    }
}

// ---------------------------------------------------------------------------
extern "C" void kernel_launch(void* const* d_in, const int* in_sizes, int n_in,
                              void* d_out, int out_size, void* d_ws, size_t ws_size,
                              hipStream_t stream) {
    const float* X = (const float*)d_in[0];  // input_data (32768,256)
    const float* R = (const float*)d_in[1];  // rand       (32768,256)
    const float* C = (const float*)d_in[2];  // codebooks  (8192,256)
    float* out = (float*)d_out;

    char* ws = (char*)d_ws;
    unsigned short* cbh = (unsigned short*)ws;             // bf16 codebooks
    float* cnorm = (float*)(ws + WS_CNORM_OFF);
    int*   hist  = (int*)(ws + WS_HIST_OFF);

    k_prep  <<<N_CODES / 4,    256, 0, stream>>>(C, cbh, cnorm, hist);
    k_argmin<<<N_TOKENS / 128, 512, 0, stream>>>(X, R, cbh, cnorm, out, hist);
    k_stats <<<1, 1024, 0, stream>>>(hist, out + (size_t)N_TOKENS * DIM);
}